// Round 1
// 804.212 us; speedup vs baseline: 1.3108x; 1.3108x over previous
//
#include <hip/hip_runtime.h>
#include <hip/hip_bf16.h>
#include <math.h>

// Problem constants: B=2, N=16384, K=24, d_points=64, d_model=128, POS_DIM=60
constexpr int BB = 2;
constexpr int NN = 16384;
constexpr int KK = 24;
constexpr int DM = 128;
constexpr int DP = 64;

constexpr int PPB = 4;           // points per fused block
constexpr int RR  = PPB * KK;    // 96 matmul rows per block (6 x 16, no pad rows)

typedef __bf16 v8bf __attribute__((ext_vector_type(8)));
typedef float  v4f  __attribute__((ext_vector_type(4)));

// A-operand LDS leading dims: +8 bf16 pad keeps 16B alignment and shifts
// consecutive rows by 4 banks -> quad-lane ds_read_b128 is only 2-way (free).
constexpr int LDA128 = 136;
constexpr int LDA64  = 72;

// bf16 weight buffer layout in ws (element offsets from wbuf):
//   fc1t 128x64 @0, d1t 128x64 @8192, d2t 128x128 @16384,
//   g1t @32768, g2t @49152, fc2t (transposed [f][g]) @65536; total 81920 bf16.
constexpr int OFF_FC1T = 0;
constexpr int OFF_D1T  = 8192;
constexpr int OFF_D2T  = 16384;
constexpr int OFF_G1T  = 32768;
constexpr int OFF_G2T  = 49152;
constexpr int OFF_FC2T = 65536;
constexpr int W_TOTAL  = 81920;

// ---------------------------------------------------------------------------
// Weight prep: transpose + cast to bf16. wbuf = d_ws + B*N*DM bf16 elems.
// ---------------------------------------------------------------------------
__global__ __launch_bounds__(256) void prep_kernel(
    const float* __restrict__ fc1_w, const float* __restrict__ fc2_w,
    const float* __restrict__ d1_w,  const float* __restrict__ d2_w,
    const float* __restrict__ g1_w,  const float* __restrict__ g2_w,
    __hip_bfloat16* __restrict__ wbuf)
{
    const int i = blockIdx.x * 256 + threadIdx.x;
    if (i >= W_TOTAL) return;
    float v;
    if (i < OFF_D1T) {                       // fc1t[n][k] = fc1_w[k][n], 64x128 src
        const int j = i, n = j >> 6, k = j & 63;
        v = fc1_w[k * DM + n];
    } else if (i < OFF_D2T) {                // d1t[n][k] = d1_w[k][n], 60x128 src, pad k>=60
        const int j = i - OFF_D1T, n = j >> 6, k = j & 63;
        v = (k < 60) ? d1_w[k * DM + n] : 0.f;
    } else if (i < OFF_G1T) {
        const int j = i - OFF_D2T, n = j >> 7, k = j & 127;
        v = d2_w[k * DM + n];
    } else if (i < OFF_G2T) {
        const int j = i - OFF_G1T, n = j >> 7, k = j & 127;
        v = g1_w[k * DM + n];
    } else if (i < OFF_FC2T) {
        const int j = i - OFF_G2T, n = j >> 7, k = j & 127;
        v = g2_w[k * DM + n];
    } else {                                 // fc2t[f][g] = fc2_w[g][f] (for vector loads)
        const int j = i - OFF_FC2T, f = j >> 7, g = j & 127;
        v = fc2_w[g * DM + f];
    }
    wbuf[i] = __float2bfloat16(v);
}

// ---------------------------------------------------------------------------
// (MT*16)x32 output tile per wave: A (LDS, bf16, padded LDA) is MT*16 rows x
// (NKT*32) k; B (global bf16, col-major rows of length LDB) cols [c0,c0+32).
// MFMA layouts (verified m89/m120):
//   A: m=lane&15, k=quad*8+j ; B: k=quad*8+j, n=lane&15 ;
//   D: row=quad*4+r, col=lane&15.
// ---------------------------------------------------------------------------
template <int MT, int NKT, int LDA, int LDB>
__device__ __forceinline__ void mm_frags(
    const __hip_bfloat16* As, const __hip_bfloat16* __restrict__ Bt,
    int c0, int lane, v4f (&acc)[MT][2])
{
    const int ln = lane & 15, quad = lane >> 4;
    #pragma unroll
    for (int mt = 0; mt < MT; ++mt) {
        acc[mt][0] = (v4f)0.f;
        acc[mt][1] = (v4f)0.f;
    }
    #pragma unroll
    for (int kt = 0; kt < NKT; ++kt) {
        const int k0 = kt * 32 + quad * 8;
        const v8bf b0 = *(const v8bf*)(Bt + (c0 + ln) * LDB + k0);
        const v8bf b1 = *(const v8bf*)(Bt + (c0 + 16 + ln) * LDB + k0);
        #pragma unroll
        for (int mt = 0; mt < MT; ++mt) {
            const v8bf a = *(const v8bf*)(As + (mt * 16 + ln) * LDA + k0);
            acc[mt][0] = __builtin_amdgcn_mfma_f32_16x16x32_bf16(a, b0, acc[mt][0], 0, 0, 0);
            acc[mt][1] = __builtin_amdgcn_mfma_f32_16x16x32_bf16(a, b1, acc[mt][1], 0, 0, 0);
        }
    }
}

// ---------------------------------------------------------------------------
// Kernel 1: x_bf = bf16(features @ fc1_w + fc1_b), 32 rows per block, MFMA.
// ---------------------------------------------------------------------------
__global__ __launch_bounds__(256) void fc1_kernel(
    const float* __restrict__ feat,
    const __hip_bfloat16* __restrict__ fc1t,
    const float* __restrict__ fc1_b,
    __hip_bfloat16* __restrict__ x_bf)
{
    __shared__ alignas(16) __hip_bfloat16 s_f[32 * LDA64];
    const int tid = threadIdx.x;
    const int r0  = blockIdx.x * 32;
    for (int e = tid; e < 32 * DP; e += 256) {
        const int r = e >> 6, k = e & 63;
        s_f[r * LDA64 + k] = __float2bfloat16(feat[(size_t)(r0 + r) * DP + k]);
    }
    __syncthreads();
    const int w = tid >> 6, lane = tid & 63;
    const int ln = lane & 15, quad = lane >> 4;
    const int c0 = w * 32;
    v4f acc[2][2];
    mm_frags<2, 2, LDA64, 64>(s_f, fc1t, c0, lane, acc);
    #pragma unroll
    for (int nl = 0; nl < 2; ++nl) {
        const int col = c0 + nl * 16 + ln;
        const float bb = fc1_b[col];
        #pragma unroll
        for (int mt = 0; mt < 2; ++mt)
            #pragma unroll
            for (int r = 0; r < 4; ++r) {
                const int row = mt * 16 + quad * 4 + r;
                x_bf[(size_t)(r0 + row) * DM + col] = __float2bfloat16(acc[mt][nl][r] + bb);
            }
    }
}

// ---------------------------------------------------------------------------
// XOR chunk swizzle for the kv buffer (row stride 256B == 0 mod 32 banks):
// permute 16B chunks within each row by row&15 so the MFMA-D-layout scalar
// epilogue accesses (4 quads at rows r..r+12, same col range) hit distinct
// bank groups. Preserves 16B alignment for vector gather stores.
// ---------------------------------------------------------------------------
__device__ __forceinline__ int zoff(int row, int col) {
    return (row << 7) + ((((col >> 3) ^ row) & 15) << 3) + (col & 7);
}

// ---------------------------------------------------------------------------
// Kernel 2: fused pipeline, PPB=4 points per block (96 matmul rows), 256 thr.
// LDS plan (78.8 KB -> 2 blocks/CU):
//   s_X 26112B : g_emb (stride LDA64) + s_idx in tail -> h -> logits
//   s_Y 26112B : t -> u -> s_res (f32, 2KB alias)
//   s_Z 24576B : kv (bf16, lossless copy of x_bf) -> kv+pe  (swizzled)
//   s_xm 2048B : center-point x rows (f32)
// Phases (6 barriers/block = 1.5/point vs 7/point before):
//   0: idx/xm/sincos   1: gather(kv)||mm1(t)   2: mm2(pe->h, kv+=pe)
//   3: mm3(u)          4: mm4(logits)          5: softmax+attn+wsum   6: fc2
// ---------------------------------------------------------------------------
__global__ __launch_bounds__(256) void fused_kernel(
    const __hip_bfloat16* __restrict__ x_bf,
    const float* __restrict__ xyz,
    const int*   __restrict__ knn_idx,
    const float* __restrict__ knn_xyz,
    const __hip_bfloat16* __restrict__ wbuf,
    const float* __restrict__ d1_b, const float* __restrict__ d2_b,
    const float* __restrict__ g1_b, const float* __restrict__ g2_b,
    const float* __restrict__ fc2_b,
    float* __restrict__ out_res,
    float* __restrict__ out_attn)
{
    __shared__ alignas(16) __hip_bfloat16 s_X[RR * LDA128];
    __shared__ alignas(16) __hip_bfloat16 s_Y[RR * LDA128];
    __shared__ alignas(16) __hip_bfloat16 s_Z[RR * DM];
    __shared__ float s_xm[PPB * DM];

    __hip_bfloat16* s_ge = s_X;                               // 96*72 els, dead after mm1
    int*   s_idx = reinterpret_cast<int*>(s_X + RR * LDA64);  // X tail, dead after gather
    float* s_res = reinterpret_cast<float*>(s_Y);             // alias, live only after mm4

    const int tid = threadIdx.x;
    const int pt0 = blockIdx.x * PPB;     // N=16384 multiple of PPB -> no batch crossing
    const int b   = pt0 >> 14;
    const int w = tid >> 6, lane = tid & 63;
    const int ln = lane & 15, quad = lane >> 4;
    const int c0 = w * 32;

    // ---- phase 0: idx, xm, sincos embedding ----
    if (tid < RR) s_idx[tid] = knn_idx[(size_t)pt0 * KK + tid];
    if (tid < PPB * DM / 8) {             // 4 center rows = 1KB contiguous bf16
        const v8bf xv = *(const v8bf*)(x_bf + (size_t)pt0 * DM + tid * 8);
        #pragma unroll
        for (int j = 0; j < 8; ++j) s_xm[tid * 8 + j] = (float)xv[j];
    }
    if (tid < RR)                         // zero k-pad cols 60..63 of g_emb
        *reinterpret_cast<uint2*>(s_ge + tid * LDA64 + 60) = make_uint2(0u, 0u);
    for (int e = tid; e < RR * 30; e += 256) {
        const int row = e / 30;
        const int rem = e - row * 30;
        const int c = rem / 10;
        const int i = rem - c * 10;
        const int g = pt0 + row / 24;
        const float pv = xyz[(size_t)g * 3 + c] - knn_xyz[((size_t)pt0 * KK + row) * 3 + c];
        const float om = exp2f(-(float)i * 1.3287712379549449f); // 10000^(-i/10)
        float sv, cv;
        __sincosf(pv * om, &sv, &cv);
        s_ge[row * LDA64 + c * 20 + i]      = __float2bfloat16(sv);
        s_ge[row * LDA64 + c * 20 + 10 + i] = __float2bfloat16(cv);
    }
    __syncthreads();

    v4f acc[6][2];

    // ---- phase 1: kv gather (issue early) || mm1: t = relu(g_emb@d1+b) -> Y
    v8bf gv[6];
    {
        const size_t xbase = (size_t)b * NN * DM;
        #pragma unroll
        for (int i = 0; i < 6; ++i) {
            const int e = tid + i * 256;
            const int row = e >> 4, part = e & 15;
            gv[i] = *(const v8bf*)(x_bf + xbase + (size_t)s_idx[row] * DM + part * 8);
        }
    }
    mm_frags<6, 2, LDA64, 64>(s_ge, wbuf + OFF_D1T, c0, lane, acc);
    #pragma unroll
    for (int i = 0; i < 6; ++i) {         // write-late: HBM latency hidden under mm1
        const int e = tid + i * 256;
        const int row = e >> 4, part = e & 15;
        *reinterpret_cast<v8bf*>(&s_Z[zoff(row, part * 8)]) = gv[i];
    }
    {
        const float bb0 = d1_b[c0 + ln], bb1 = d1_b[c0 + 16 + ln];
        #pragma unroll
        for (int mt = 0; mt < 6; ++mt) {
            const int row0 = mt * 16 + quad * 4;
            #pragma unroll
            for (int r = 0; r < 4; ++r) {
                s_Y[(row0 + r) * LDA128 + c0 + ln]      = __float2bfloat16(fmaxf(acc[mt][0][r] + bb0, 0.f));
                s_Y[(row0 + r) * LDA128 + c0 + 16 + ln] = __float2bfloat16(fmaxf(acc[mt][1][r] + bb1, 0.f));
            }
        }
    }
    __syncthreads();

    // ---- phase 2: pe = t@d2+b; h = xm - kv + pe -> X; Z <- kv+pe ----
    mm_frags<6, 4, LDA128, DM>(s_Y, wbuf + OFF_D2T, c0, lane, acc);
    {
        const float bb0 = d2_b[c0 + ln], bb1 = d2_b[c0 + 16 + ln];
        #pragma unroll
        for (int mt = 0; mt < 6; ++mt) {
            const int row0 = mt * 16 + quad * 4;    // 4-row group never crosses a point
            const int p = row0 / 24;
            const float xm0 = s_xm[p * DM + c0 + ln];
            const float xm1 = s_xm[p * DM + c0 + 16 + ln];
            #pragma unroll
            for (int r = 0; r < 4; ++r) {
                const int row = row0 + r;
                const int zo0 = zoff(row, c0 + ln);
                const int zo1 = zoff(row, c0 + 16 + ln);
                const float pe0 = acc[mt][0][r] + bb0;
                const float pe1 = acc[mt][1][r] + bb1;
                const float kv0 = __bfloat162float(s_Z[zo0]);
                const float kv1 = __bfloat162float(s_Z[zo1]);
                s_X[row * LDA128 + c0 + ln]      = __float2bfloat16(xm0 - kv0 + pe0);
                s_X[row * LDA128 + c0 + 16 + ln] = __float2bfloat16(xm1 - kv1 + pe1);
                s_Z[zo0] = __float2bfloat16(kv0 + pe0);
                s_Z[zo1] = __float2bfloat16(kv1 + pe1);
            }
        }
    }
    __syncthreads();

    // ---- phase 3: u = relu(h@g1+b) -> Y ----
    mm_frags<6, 4, LDA128, DM>(s_X, wbuf + OFF_G1T, c0, lane, acc);
    {
        const float bb0 = g1_b[c0 + ln], bb1 = g1_b[c0 + 16 + ln];
        #pragma unroll
        for (int mt = 0; mt < 6; ++mt) {
            const int row0 = mt * 16 + quad * 4;
            #pragma unroll
            for (int r = 0; r < 4; ++r) {
                s_Y[(row0 + r) * LDA128 + c0 + ln]      = __float2bfloat16(fmaxf(acc[mt][0][r] + bb0, 0.f));
                s_Y[(row0 + r) * LDA128 + c0 + 16 + ln] = __float2bfloat16(fmaxf(acc[mt][1][r] + bb1, 0.f));
            }
        }
    }
    __syncthreads();

    // ---- phase 4: logits = (u@g2+b)/sqrt(128) -> X ----
    mm_frags<6, 4, LDA128, DM>(s_Y, wbuf + OFF_G2T, c0, lane, acc);
    {
        const float iscl = 0.08838834764831845f;
        const float bb0 = g2_b[c0 + ln], bb1 = g2_b[c0 + 16 + ln];
        #pragma unroll
        for (int mt = 0; mt < 6; ++mt) {
            const int row0 = mt * 16 + quad * 4;
            #pragma unroll
            for (int r = 0; r < 4; ++r) {
                s_X[(row0 + r) * LDA128 + c0 + ln]      = __float2bfloat16((acc[mt][0][r] + bb0) * iscl);
                s_X[(row0 + r) * LDA128 + c0 + 16 + ln] = __float2bfloat16((acc[mt][1][r] + bb1) * iscl);
            }
        }
    }
    __syncthreads();

    // ---- phase 5: softmax over K per channel + attn write + weighted sum ----
    #pragma unroll
    for (int cc = 0; cc < 2; ++cc) {
        const int ch = cc * 256 + tid;        // 512 channels, all threads active
        const int p = ch >> 7, f = ch & 127;
        const int rbase = p * KK;
        float lv[KK];
        float mx = -1e30f;
        #pragma unroll
        for (int n = 0; n < KK; ++n) {
            lv[n] = __bfloat162float(s_X[(rbase + n) * LDA128 + f]);
            mx = fmaxf(mx, lv[n]);
        }
        float sum = 0.f;
        #pragma unroll
        for (int n = 0; n < KK; ++n) {
            const float ev = __expf(lv[n] - mx);
            lv[n] = ev;
            sum += ev;
        }
        const float inv = 1.f / sum;
        float racc = 0.f;
        float* ab = out_attn + (size_t)(pt0 + p) * KK * DM + f;
        #pragma unroll
        for (int n = 0; n < KK; ++n) {
            const float a = lv[n] * inv;
            ab[n * DM] = a;
            racc = fmaf(a, __bfloat162float(s_Z[zoff(rbase + n, f)]), racc);
        }
        s_res[ch] = racc;                     // s_res aliases dead u-buffer
    }
    __syncthreads();

    // ---- phase 6: res @ fc2t (vectorized rows) + bias + x ----
    #pragma unroll
    for (int cc = 0; cc < 2; ++cc) {
        const int ch = cc * 256 + tid;
        const int p = ch >> 7, f = ch & 127;
        const v8bf* wr = reinterpret_cast<const v8bf*>(wbuf + OFF_FC2T + f * DM);
        float a2 = 0.f;
        #pragma unroll
        for (int g8 = 0; g8 < 16; ++g8) {
            const v8bf wv = wr[g8];
            const v4f r0 = *(const v4f*)(s_res + p * DM + g8 * 8);
            const v4f r1 = *(const v4f*)(s_res + p * DM + g8 * 8 + 4);
            #pragma unroll
            for (int j = 0; j < 4; ++j) {
                a2 = fmaf(r0[j], (float)wv[j], a2);
                a2 = fmaf(r1[j], (float)wv[j + 4], a2);
            }
        }
        out_res[(size_t)(pt0 + p) * DM + f] = a2 + fc2_b[f] + s_xm[p * DM + f];
    }
}

// ---------------------------------------------------------------------------
extern "C" void kernel_launch(void* const* d_in, const int* in_sizes, int n_in,
                              void* d_out, int out_size, void* d_ws, size_t ws_size,
                              hipStream_t stream)
{
    const float* features = (const float*)d_in[0];
    const float* xyz      = (const float*)d_in[1];
    const int*   knn_idx  = (const int*)  d_in[2];
    const float* knn_xyz  = (const float*)d_in[3];
    const float* fc1_w    = (const float*)d_in[4];
    const float* fc1_b    = (const float*)d_in[5];
    const float* fc2_w    = (const float*)d_in[6];
    const float* fc2_b    = (const float*)d_in[7];
    const float* d1_w     = (const float*)d_in[8];
    const float* d1_b     = (const float*)d_in[9];
    const float* d2_w     = (const float*)d_in[10];
    const float* d2_b     = (const float*)d_in[11];
    const float* g1_w     = (const float*)d_in[12];
    const float* g1_b     = (const float*)d_in[13];
    const float* g2_w     = (const float*)d_in[14];
    const float* g2_b     = (const float*)d_in[15];

    __hip_bfloat16* x_bf = (__hip_bfloat16*)d_ws;                  // B*N*128 bf16 = 8 MB
    __hip_bfloat16* wbuf = x_bf + (size_t)BB * NN * DM;            // 160 KB bf16 weights
    float* out_res  = (float*)d_out;
    float* out_attn = out_res + (size_t)BB * NN * DM;

    prep_kernel<<<(W_TOTAL + 255) / 256, 256, 0, stream>>>(
        fc1_w, fc2_w, d1_w, d2_w, g1_w, g2_w, wbuf);
    fc1_kernel<<<(BB * NN) / 32, 256, 0, stream>>>(
        features, wbuf + OFF_FC1T, fc1_b, x_bf);
    fused_kernel<<<(BB * NN) / PPB, 256, 0, stream>>>(
        x_bf, xyz, knn_idx, knn_xyz, wbuf,
        d1_b, d2_b, g1_b, g2_b, fc2_b, out_res, out_attn);
}

// Round 2
// 675.896 us; speedup vs baseline: 1.5597x; 1.1898x over previous
//
#include <hip/hip_runtime.h>
#include <hip/hip_bf16.h>
#include <math.h>

// Problem constants: B=2, N=16384, K=24, d_points=64, d_model=128, POS_DIM=60
constexpr int BB = 2;
constexpr int NN = 16384;
constexpr int KK = 24;
constexpr int DM = 128;
constexpr int DP = 64;

constexpr int PPB = 4;           // points per fused block
constexpr int RR  = PPB * KK;    // 96 matmul rows per block (6 x 16, no pad rows)

typedef __bf16 v8bf __attribute__((ext_vector_type(8)));
typedef float  v4f  __attribute__((ext_vector_type(4)));

// A-operand LDS leading dims: +8 bf16 pad keeps 16B alignment and shifts
// consecutive rows by 4 banks -> quad-lane ds_read_b128 is only 2-way (free).
constexpr int LDA128 = 136;
constexpr int LDA64  = 72;

// bf16 weight buffer layout in ws (element offsets from wbuf):
//   fc1t 128x64 @0, d1t 128x64 @8192, d2t 128x128 @16384,
//   g1t @32768, g2t @49152, fc2t (transposed [f][g]) @65536; total 81920 bf16.
constexpr int OFF_FC1T = 0;
constexpr int OFF_D1T  = 8192;
constexpr int OFF_D2T  = 16384;
constexpr int OFF_G1T  = 32768;
constexpr int OFF_G2T  = 49152;
constexpr int OFF_FC2T = 65536;
constexpr int W_TOTAL  = 81920;

// ---------------------------------------------------------------------------
// Weight prep: transpose + cast to bf16. wbuf = d_ws + B*N*DM bf16 elems.
// ---------------------------------------------------------------------------
__global__ __launch_bounds__(256) void prep_kernel(
    const float* __restrict__ fc1_w, const float* __restrict__ fc2_w,
    const float* __restrict__ d1_w,  const float* __restrict__ d2_w,
    const float* __restrict__ g1_w,  const float* __restrict__ g2_w,
    __hip_bfloat16* __restrict__ wbuf)
{
    const int i = blockIdx.x * 256 + threadIdx.x;
    if (i >= W_TOTAL) return;
    float v;
    if (i < OFF_D1T) {                       // fc1t[n][k] = fc1_w[k][n], 64x128 src
        const int j = i, n = j >> 6, k = j & 63;
        v = fc1_w[k * DM + n];
    } else if (i < OFF_D2T) {                // d1t[n][k] = d1_w[k][n], 60x128 src, pad k>=60
        const int j = i - OFF_D1T, n = j >> 6, k = j & 63;
        v = (k < 60) ? d1_w[k * DM + n] : 0.f;
    } else if (i < OFF_G1T) {
        const int j = i - OFF_D2T, n = j >> 7, k = j & 127;
        v = d2_w[k * DM + n];
    } else if (i < OFF_G2T) {
        const int j = i - OFF_G1T, n = j >> 7, k = j & 127;
        v = g1_w[k * DM + n];
    } else if (i < OFF_FC2T) {
        const int j = i - OFF_G2T, n = j >> 7, k = j & 127;
        v = g2_w[k * DM + n];
    } else {                                 // fc2t[f][g] = fc2_w[g][f] (for vector loads / MFMA B)
        const int j = i - OFF_FC2T, f = j >> 7, g = j & 127;
        v = fc2_w[g * DM + f];
    }
    wbuf[i] = __float2bfloat16(v);
}

// ---------------------------------------------------------------------------
// (MT*16)x32 output tile per wave: A (LDS, bf16, padded LDA) is MT*16 rows x
// (NKT*32) k; B (global bf16, col-major rows of length LDB) cols [c0,c0+32).
// MFMA layouts (verified m89/m120):
//   A: m=lane&15, k=quad*8+j ; B: k=quad*8+j, n=lane&15 ;
//   D: row=quad*4+r, col=lane&15.
// setprio(1) while in the MFMA-dense region: with 3 independent blocks/CU at
// different phases the CU scheduler can favor the compute-phase wave (T5).
// ---------------------------------------------------------------------------
template <int MT, int NKT, int LDA, int LDB>
__device__ __forceinline__ void mm_frags(
    const __hip_bfloat16* As, const __hip_bfloat16* __restrict__ Bt,
    int c0, int lane, v4f (&acc)[MT][2])
{
    const int ln = lane & 15, quad = lane >> 4;
    #pragma unroll
    for (int mt = 0; mt < MT; ++mt) {
        acc[mt][0] = (v4f)0.f;
        acc[mt][1] = (v4f)0.f;
    }
    __builtin_amdgcn_s_setprio(1);
    #pragma unroll
    for (int kt = 0; kt < NKT; ++kt) {
        const int k0 = kt * 32 + quad * 8;
        const v8bf b0 = *(const v8bf*)(Bt + (c0 + ln) * LDB + k0);
        const v8bf b1 = *(const v8bf*)(Bt + (c0 + 16 + ln) * LDB + k0);
        #pragma unroll
        for (int mt = 0; mt < MT; ++mt) {
            const v8bf a = *(const v8bf*)(As + (mt * 16 + ln) * LDA + k0);
            acc[mt][0] = __builtin_amdgcn_mfma_f32_16x16x32_bf16(a, b0, acc[mt][0], 0, 0, 0);
            acc[mt][1] = __builtin_amdgcn_mfma_f32_16x16x32_bf16(a, b1, acc[mt][1], 0, 0, 0);
        }
    }
    __builtin_amdgcn_s_setprio(0);
}

// ---------------------------------------------------------------------------
// Kernel 1: x_bf = bf16(features @ fc1_w + fc1_b), 32 rows per block, MFMA.
// ---------------------------------------------------------------------------
__global__ __launch_bounds__(256) void fc1_kernel(
    const float* __restrict__ feat,
    const __hip_bfloat16* __restrict__ fc1t,
    const float* __restrict__ fc1_b,
    __hip_bfloat16* __restrict__ x_bf)
{
    __shared__ alignas(16) __hip_bfloat16 s_f[32 * LDA64];
    const int tid = threadIdx.x;
    const int r0  = blockIdx.x * 32;
    for (int e = tid; e < 32 * DP; e += 256) {
        const int r = e >> 6, k = e & 63;
        s_f[r * LDA64 + k] = __float2bfloat16(feat[(size_t)(r0 + r) * DP + k]);
    }
    __syncthreads();
    const int w = tid >> 6, lane = tid & 63;
    const int ln = lane & 15, quad = lane >> 4;
    const int c0 = w * 32;
    v4f acc[2][2];
    mm_frags<2, 2, LDA64, 64>(s_f, fc1t, c0, lane, acc);
    #pragma unroll
    for (int nl = 0; nl < 2; ++nl) {
        const int col = c0 + nl * 16 + ln;
        const float bb = fc1_b[col];
        #pragma unroll
        for (int mt = 0; mt < 2; ++mt)
            #pragma unroll
            for (int r = 0; r < 4; ++r) {
                const int row = mt * 16 + quad * 4 + r;
                x_bf[(size_t)(r0 + row) * DM + col] = __float2bfloat16(acc[mt][nl][r] + bb);
            }
    }
}

// ---------------------------------------------------------------------------
// XOR chunk swizzle for the kv buffer (row stride 256B == 0 mod 32 banks):
// permute 16B chunks within each row by row&15 so the MFMA-D-layout scalar
// epilogue accesses (4 quads at rows r..r+12, same col range) hit distinct
// bank groups. Preserves 16B alignment for vector gather stores.
// ---------------------------------------------------------------------------
__device__ __forceinline__ int zoff(int row, int col) {
    return (row << 7) + ((((col >> 3) ^ row) & 15) << 3) + (col & 7);
}

// ---------------------------------------------------------------------------
// Kernel 2: fused pipeline, PPB=4 points (96 rows), 256 thr.
// LDS plan (51,712 B -> 3 blocks/CU = 12 waves):
//   s_A 26112B : ge (stride LDA64, idx in tail) -> t -> h -> u -> logits
//                -> res16 (rows 0..3, bf16)   [single in-place buffer]
//   s_Z 24576B : kv (bf16, swizzled) -> kv+pe
//   s_xm 1024B : center-point x rows (bf16 — lossless, source is bf16)
// In-place discipline: mm_frags reads -> barrier -> epilogue writes -> barrier.
// Accumulators stay in registers across the barriers.
// Phases: 0 idx/xm/sincos | 1 gather||mm1(t) | 2 mm2(pe->h, kv+=pe)
//         3 mm3(u) | 4 mm4(logits) | 5 softmax+attn+wsum -> res16 | 6 fc2 MFMA
// ---------------------------------------------------------------------------
__global__ __launch_bounds__(256, 3) void fused_kernel(
    const __hip_bfloat16* __restrict__ x_bf,
    const float* __restrict__ xyz,
    const int*   __restrict__ knn_idx,
    const float* __restrict__ knn_xyz,
    const __hip_bfloat16* __restrict__ wbuf,
    const float* __restrict__ d1_b, const float* __restrict__ d2_b,
    const float* __restrict__ g1_b, const float* __restrict__ g2_b,
    const float* __restrict__ fc2_b,
    float* __restrict__ out_res,
    float* __restrict__ out_attn)
{
    __shared__ alignas(16) __hip_bfloat16 s_A[RR * LDA128];
    __shared__ alignas(16) __hip_bfloat16 s_Z[RR * DM];
    __shared__ alignas(16) __hip_bfloat16 s_xm[PPB * DM];

    __hip_bfloat16* s_ge = s_A;                               // stride LDA64, dead after mm1
    int* s_idx = reinterpret_cast<int*>(s_A + RR * LDA64);    // tail, dead after gather issue

    const int tid = threadIdx.x;
    const int pt0 = blockIdx.x * PPB;     // N multiple of PPB -> no batch crossing
    const int b   = pt0 >> 14;
    const int w = tid >> 6, lane = tid & 63;
    const int ln = lane & 15, quad = lane >> 4;
    const int c0 = w * 32;

    // ---- phase 0: idx, xm, sincos embedding ----
    if (tid < RR) s_idx[tid] = knn_idx[(size_t)pt0 * KK + tid];
    if (tid < PPB * DM / 8)               // 4 center rows = 1KB contiguous bf16 copy
        *reinterpret_cast<v8bf*>(s_xm + tid * 8) =
            *(const v8bf*)(x_bf + (size_t)pt0 * DM + tid * 8);
    if (tid < RR)                         // zero k-pad cols 60..63 of g_emb
        *reinterpret_cast<uint2*>(s_ge + tid * LDA64 + 60) = make_uint2(0u, 0u);
    for (int e = tid; e < RR * 30; e += 256) {
        const int row = e / 30;
        const int rem = e - row * 30;
        const int c = rem / 10;
        const int i = rem - c * 10;
        const int g = pt0 + row / 24;
        const float pv = xyz[(size_t)g * 3 + c] - knn_xyz[((size_t)pt0 * KK + row) * 3 + c];
        const float om = exp2f(-(float)i * 1.3287712379549449f); // 10000^(-i/10)
        float sv, cv;
        __sincosf(pv * om, &sv, &cv);
        s_ge[row * LDA64 + c * 20 + i]      = __float2bfloat16(sv);
        s_ge[row * LDA64 + c * 20 + 10 + i] = __float2bfloat16(cv);
    }
    __syncthreads();

    v4f acc[6][2];

    // ---- phase 1: kv gather (issue early) || mm1: t = relu(ge@d1+b) ----
    v8bf gv[6];
    {
        const size_t xbase = (size_t)b * NN * DM;
        #pragma unroll
        for (int i = 0; i < 6; ++i) {
            const int e = tid + i * 256;
            const int row = e >> 4, part = e & 15;
            gv[i] = *(const v8bf*)(x_bf + xbase + (size_t)s_idx[row] * DM + part * 8);
        }
    }
    mm_frags<6, 2, LDA64, 64>(s_A, wbuf + OFF_D1T, c0, lane, acc);
    #pragma unroll
    for (int i = 0; i < 6; ++i) {         // write-late: HBM latency hidden under mm1
        const int e = tid + i * 256;
        const int row = e >> 4, part = e & 15;
        *reinterpret_cast<v8bf*>(&s_Z[zoff(row, part * 8)]) = gv[i];
    }
    __syncthreads();                      // all ge reads done -> safe to overwrite s_A
    {
        const float bb0 = d1_b[c0 + ln], bb1 = d1_b[c0 + 16 + ln];
        #pragma unroll
        for (int mt = 0; mt < 6; ++mt) {
            const int row0 = mt * 16 + quad * 4;
            #pragma unroll
            for (int r = 0; r < 4; ++r) {
                s_A[(row0 + r) * LDA128 + c0 + ln]      = __float2bfloat16(fmaxf(acc[mt][0][r] + bb0, 0.f));
                s_A[(row0 + r) * LDA128 + c0 + 16 + ln] = __float2bfloat16(fmaxf(acc[mt][1][r] + bb1, 0.f));
            }
        }
    }
    __syncthreads();

    // ---- phase 2: pe = t@d2+b; h = xm - kv + pe -> A; Z <- kv+pe ----
    mm_frags<6, 4, LDA128, DM>(s_A, wbuf + OFF_D2T, c0, lane, acc);
    __syncthreads();                      // all t reads done
    {
        const float bb0 = d2_b[c0 + ln], bb1 = d2_b[c0 + 16 + ln];
        #pragma unroll
        for (int mt = 0; mt < 6; ++mt) {
            const int row0 = mt * 16 + quad * 4;    // 4-row group never crosses a point
            const int p = row0 / 24;
            const float xm0 = __bfloat162float(s_xm[p * DM + c0 + ln]);
            const float xm1 = __bfloat162float(s_xm[p * DM + c0 + 16 + ln]);
            #pragma unroll
            for (int r = 0; r < 4; ++r) {
                const int row = row0 + r;
                const int zo0 = zoff(row, c0 + ln);
                const int zo1 = zoff(row, c0 + 16 + ln);
                const float pe0 = acc[mt][0][r] + bb0;
                const float pe1 = acc[mt][1][r] + bb1;
                const float kv0 = __bfloat162float(s_Z[zo0]);
                const float kv1 = __bfloat162float(s_Z[zo1]);
                s_A[row * LDA128 + c0 + ln]      = __float2bfloat16(xm0 - kv0 + pe0);
                s_A[row * LDA128 + c0 + 16 + ln] = __float2bfloat16(xm1 - kv1 + pe1);
                s_Z[zo0] = __float2bfloat16(kv0 + pe0);
                s_Z[zo1] = __float2bfloat16(kv1 + pe1);
            }
        }
    }
    __syncthreads();

    // ---- phase 3: u = relu(h@g1+b) -> A ----
    mm_frags<6, 4, LDA128, DM>(s_A, wbuf + OFF_G1T, c0, lane, acc);
    __syncthreads();
    {
        const float bb0 = g1_b[c0 + ln], bb1 = g1_b[c0 + 16 + ln];
        #pragma unroll
        for (int mt = 0; mt < 6; ++mt) {
            const int row0 = mt * 16 + quad * 4;
            #pragma unroll
            for (int r = 0; r < 4; ++r) {
                s_A[(row0 + r) * LDA128 + c0 + ln]      = __float2bfloat16(fmaxf(acc[mt][0][r] + bb0, 0.f));
                s_A[(row0 + r) * LDA128 + c0 + 16 + ln] = __float2bfloat16(fmaxf(acc[mt][1][r] + bb1, 0.f));
            }
        }
    }
    __syncthreads();

    // ---- phase 4: logits = (u@g2+b)/sqrt(128) -> A ----
    mm_frags<6, 4, LDA128, DM>(s_A, wbuf + OFF_G2T, c0, lane, acc);
    __syncthreads();
    {
        const float iscl = 0.08838834764831845f;
        const float bb0 = g2_b[c0 + ln], bb1 = g2_b[c0 + 16 + ln];
        #pragma unroll
        for (int mt = 0; mt < 6; ++mt) {
            const int row0 = mt * 16 + quad * 4;
            #pragma unroll
            for (int r = 0; r < 4; ++r) {
                s_A[(row0 + r) * LDA128 + c0 + ln]      = __float2bfloat16((acc[mt][0][r] + bb0) * iscl);
                s_A[(row0 + r) * LDA128 + c0 + 16 + ln] = __float2bfloat16((acc[mt][1][r] + bb1) * iscl);
            }
        }
    }
    __syncthreads();

    // ---- phase 5: softmax over K per channel + attn write + weighted sum ----
    float rres[2];
    #pragma unroll
    for (int cc = 0; cc < 2; ++cc) {
        const int ch = cc * 256 + tid;        // 512 channels, all threads active
        const int p = ch >> 7, f = ch & 127;
        const int rbase = p * KK;
        float lv[KK];
        float mx = -1e30f;
        #pragma unroll
        for (int n = 0; n < KK; ++n) {
            lv[n] = __bfloat162float(s_A[(rbase + n) * LDA128 + f]);
            mx = fmaxf(mx, lv[n]);
        }
        float sum = 0.f;
        #pragma unroll
        for (int n = 0; n < KK; ++n) {
            const float ev = __expf(lv[n] - mx);
            lv[n] = ev;
            sum += ev;
        }
        const float inv = 1.f / sum;
        float racc = 0.f;
        float* ab = out_attn + (size_t)(pt0 + p) * KK * DM + f;
        #pragma unroll
        for (int n = 0; n < KK; ++n) {
            const float a = lv[n] * inv;
            ab[n * DM] = a;
            racc = fmaf(a, __bfloat162float(s_Z[zoff(rbase + n, f)]), racc);
        }
        rres[cc] = racc;
    }
    __syncthreads();                      // all logits reads done -> reuse s_A rows 0..3
    #pragma unroll
    for (int cc = 0; cc < 2; ++cc) {      // res16: 4 real rows; rows 4..15 hold stale
        const int ch = cc * 256 + tid;    // finite logits -> their MFMA outputs discarded
        const int p = ch >> 7, f = ch & 127;
        s_A[p * LDA128 + f] = __float2bfloat16(rres[cc]);
    }
    __syncthreads();

    // ---- phase 6: out_res rows = res16 @ fc2t via one 16-row MFMA tile ----
    {
        v4f a2[1][2];
        mm_frags<1, 4, LDA128, DM>(s_A, wbuf + OFF_FC2T, c0, lane, a2);
        if (quad == 0) {                  // D rows 0..3 are the real points
            #pragma unroll
            for (int nl = 0; nl < 2; ++nl) {
                const int col = c0 + nl * 16 + ln;
                const float bb = fc2_b[col];
                #pragma unroll
                for (int r = 0; r < 4; ++r)
                    out_res[(size_t)(pt0 + r) * DM + col] =
                        a2[0][nl][r] + bb + __bfloat162float(s_xm[r * DM + col]);
            }
        }
    }
}

// ---------------------------------------------------------------------------
extern "C" void kernel_launch(void* const* d_in, const int* in_sizes, int n_in,
                              void* d_out, int out_size, void* d_ws, size_t ws_size,
                              hipStream_t stream)
{
    const float* features = (const float*)d_in[0];
    const float* xyz      = (const float*)d_in[1];
    const int*   knn_idx  = (const int*)  d_in[2];
    const float* knn_xyz  = (const float*)d_in[3];
    const float* fc1_w    = (const float*)d_in[4];
    const float* fc1_b    = (const float*)d_in[5];
    const float* fc2_w    = (const float*)d_in[6];
    const float* fc2_b    = (const float*)d_in[7];
    const float* d1_w     = (const float*)d_in[8];
    const float* d1_b     = (const float*)d_in[9];
    const float* d2_w     = (const float*)d_in[10];
    const float* d2_b     = (const float*)d_in[11];
    const float* g1_w     = (const float*)d_in[12];
    const float* g1_b     = (const float*)d_in[13];
    const float* g2_w     = (const float*)d_in[14];
    const float* g2_b     = (const float*)d_in[15];

    __hip_bfloat16* x_bf = (__hip_bfloat16*)d_ws;                  // B*N*128 bf16 = 8 MB
    __hip_bfloat16* wbuf = x_bf + (size_t)BB * NN * DM;            // 160 KB bf16 weights
    float* out_res  = (float*)d_out;
    float* out_attn = out_res + (size_t)BB * NN * DM;

    prep_kernel<<<(W_TOTAL + 255) / 256, 256, 0, stream>>>(
        fc1_w, fc2_w, d1_w, d2_w, g1_w, g2_w, wbuf);
    fc1_kernel<<<(BB * NN) / 32, 256, 0, stream>>>(
        features, wbuf + OFF_FC1T, fc1_b, x_bf);
    fused_kernel<<<(BB * NN) / PPB, 256, 0, stream>>>(
        x_bf, xyz, knn_idx, knn_xyz, wbuf,
        d1_b, d2_b, g1_b, g2_b, fc2_b, out_res, out_attn);
}

// Round 3
// 670.514 us; speedup vs baseline: 1.5722x; 1.0080x over previous
//
#include <hip/hip_runtime.h>
#include <hip/hip_bf16.h>
#include <math.h>

// Problem constants: B=2, N=16384, K=24, d_points=64, d_model=128, POS_DIM=60
constexpr int BB = 2;
constexpr int NN = 16384;
constexpr int KK = 24;
constexpr int DM = 128;
constexpr int DP = 64;

constexpr int PPB = 4;           // points per fused block
constexpr int RR  = PPB * KK;    // 96 matmul rows per block (6 x 16, no pad rows)

typedef __bf16 v8bf __attribute__((ext_vector_type(8)));
typedef float  v4f  __attribute__((ext_vector_type(4)));

// A-operand LDS leading dims: +8 bf16 pad keeps 16B alignment and shifts
// consecutive rows by 4 banks -> quad-lane ds_read_b128 is only 2-way (free).
constexpr int LDA128 = 136;
constexpr int LDA64  = 72;

// bf16 weight buffer layout in ws (element offsets from wbuf):
//   fc1t 128x64 @0, d1t 128x64 @8192, d2t 128x128 @16384,
//   g1t @32768, g2t @49152, fc2t (transposed [f][g]) @65536; total 81920 bf16.
constexpr int OFF_FC1T = 0;
constexpr int OFF_D1T  = 8192;
constexpr int OFF_D2T  = 16384;
constexpr int OFF_G1T  = 32768;
constexpr int OFF_G2T  = 49152;
constexpr int OFF_FC2T = 65536;
constexpr int W_TOTAL  = 81920;

// ---------------------------------------------------------------------------
// Weight prep: transpose + cast to bf16. wbuf = d_ws + B*N*DM bf16 elems.
// ---------------------------------------------------------------------------
__global__ __launch_bounds__(256) void prep_kernel(
    const float* __restrict__ fc1_w, const float* __restrict__ fc2_w,
    const float* __restrict__ d1_w,  const float* __restrict__ d2_w,
    const float* __restrict__ g1_w,  const float* __restrict__ g2_w,
    __hip_bfloat16* __restrict__ wbuf)
{
    const int i = blockIdx.x * 256 + threadIdx.x;
    if (i >= W_TOTAL) return;
    float v;
    if (i < OFF_D1T) {                       // fc1t[n][k] = fc1_w[k][n], 64x128 src
        const int j = i, n = j >> 6, k = j & 63;
        v = fc1_w[k * DM + n];
    } else if (i < OFF_D2T) {                // d1t[n][k] = d1_w[k][n], 60x128 src, pad k>=60
        const int j = i - OFF_D1T, n = j >> 6, k = j & 63;
        v = (k < 60) ? d1_w[k * DM + n] : 0.f;
    } else if (i < OFF_G1T) {
        const int j = i - OFF_D2T, n = j >> 7, k = j & 127;
        v = d2_w[k * DM + n];
    } else if (i < OFF_G2T) {
        const int j = i - OFF_G1T, n = j >> 7, k = j & 127;
        v = g1_w[k * DM + n];
    } else if (i < OFF_FC2T) {
        const int j = i - OFF_G2T, n = j >> 7, k = j & 127;
        v = g2_w[k * DM + n];
    } else {                                 // fc2t[f][g] = fc2_w[g][f]
        const int j = i - OFF_FC2T, f = j >> 7, g = j & 127;
        v = fc2_w[g * DM + f];
    }
    wbuf[i] = __float2bfloat16(v);
}

// ---------------------------------------------------------------------------
// (MT*16)x32 output tile per wave: A (LDS, bf16, padded LDA) is MT*16 rows x
// (NKT*32) k; B (global bf16, col-major rows of length LDB) cols [c0,c0+32).
// MFMA layouts (verified m89/m120):
//   A: m=lane&15, k=quad*8+j ; B: k=quad*8+j, n=lane&15 ;
//   D: row=quad*4+r, col=lane&15.
// ---------------------------------------------------------------------------
template <int MT, int NKT, int LDA, int LDB>
__device__ __forceinline__ void mm_frags(
    const __hip_bfloat16* As, const __hip_bfloat16* __restrict__ Bt,
    int c0, int lane, v4f (&acc)[MT][2])
{
    const int ln = lane & 15, quad = lane >> 4;
    #pragma unroll
    for (int mt = 0; mt < MT; ++mt) {
        acc[mt][0] = (v4f)0.f;
        acc[mt][1] = (v4f)0.f;
    }
    __builtin_amdgcn_s_setprio(1);
    #pragma unroll
    for (int kt = 0; kt < NKT; ++kt) {
        const int k0 = kt * 32 + quad * 8;
        const v8bf b0 = *(const v8bf*)(Bt + (c0 + ln) * LDB + k0);
        const v8bf b1 = *(const v8bf*)(Bt + (c0 + 16 + ln) * LDB + k0);
        #pragma unroll
        for (int mt = 0; mt < MT; ++mt) {
            const v8bf a = *(const v8bf*)(As + (mt * 16 + ln) * LDA + k0);
            acc[mt][0] = __builtin_amdgcn_mfma_f32_16x16x32_bf16(a, b0, acc[mt][0], 0, 0, 0);
            acc[mt][1] = __builtin_amdgcn_mfma_f32_16x16x32_bf16(a, b1, acc[mt][1], 0, 0, 0);
        }
    }
    __builtin_amdgcn_s_setprio(0);
}

// ---------------------------------------------------------------------------
// Kernel 1: x_bf = bf16(features @ fc1_w + fc1_b), 32 rows per block, MFMA.
// ---------------------------------------------------------------------------
__global__ __launch_bounds__(256) void fc1_kernel(
    const float* __restrict__ feat,
    const __hip_bfloat16* __restrict__ fc1t,
    const float* __restrict__ fc1_b,
    __hip_bfloat16* __restrict__ x_bf)
{
    __shared__ alignas(16) __hip_bfloat16 s_f[32 * LDA64];
    const int tid = threadIdx.x;
    const int r0  = blockIdx.x * 32;
    for (int e = tid; e < 32 * DP; e += 256) {
        const int r = e >> 6, k = e & 63;
        s_f[r * LDA64 + k] = __float2bfloat16(feat[(size_t)(r0 + r) * DP + k]);
    }
    __syncthreads();
    const int w = tid >> 6, lane = tid & 63;
    const int ln = lane & 15, quad = lane >> 4;
    const int c0 = w * 32;
    v4f acc[2][2];
    mm_frags<2, 2, LDA64, 64>(s_f, fc1t, c0, lane, acc);
    #pragma unroll
    for (int nl = 0; nl < 2; ++nl) {
        const int col = c0 + nl * 16 + ln;
        const float bb = fc1_b[col];
        #pragma unroll
        for (int mt = 0; mt < 2; ++mt)
            #pragma unroll
            for (int r = 0; r < 4; ++r) {
                const int row = mt * 16 + quad * 4 + r;
                x_bf[(size_t)(r0 + row) * DM + col] = __float2bfloat16(acc[mt][nl][r] + bb);
            }
    }
}

// ---------------------------------------------------------------------------
// XOR chunk swizzle for the kv buffer (row stride 256B == 0 mod 32 banks).
// Hash (row + row>>3)&15: rows 4 apart (the 4 quads at fixed r) land on
// distinct chunk mod 8 -> distinct bank groups (old row&15 hash aliased
// quad0/quad2 and quad1/quad3 2-way). Bijective per row; 16B chunks keep
// vector gather stores aligned.
// ---------------------------------------------------------------------------
__device__ __forceinline__ int zoff(int row, int col) {
    const int h = (row + (row >> 3)) & 15;
    return (row << 7) + ((((col >> 3) ^ h) & 15) << 3) + (col & 7);
}

// pack 2 f32 -> 1 u32 of 2 bf16 (RNE, same numerics as the old LDS round-trip)
__device__ __forceinline__ unsigned pk2(float a, float b) {
    __hip_bfloat16 ha = __float2bfloat16(a), hb = __float2bfloat16(b);
    unsigned ua = *reinterpret_cast<unsigned short*>(&ha);
    unsigned ub = *reinterpret_cast<unsigned short*>(&hb);
    return ua | (ub << 16);
}
__device__ __forceinline__ float unlo(unsigned u) {
    unsigned v = u << 16; return *reinterpret_cast<float*>(&v);
}
__device__ __forceinline__ float unhi(unsigned u) {
    unsigned v = u & 0xffff0000u; return *reinterpret_cast<float*>(&v);
}

// ---------------------------------------------------------------------------
// Kernel 2: fused pipeline, PPB=4 points (96 rows), 256 thr, 3 blocks/CU.
// LDS (51,712 B): s_A (in-place matmul buffer) + s_Z (raw kv, swizzled,
// read once) + s_xm. Softmax/attn/weighted-sum now ENTIRELY in registers:
// logits stay in MFMA accumulators (f32), per-point max/sum reduced with
// shfl_xor(16/32); kv+pe is carried from phase 2 in 24 packed-bf16 VGPRs.
// Point routing per mt is static; straddler mts (1,4) route by quad<2
// cndmask (no runtime-indexed register arrays).
// Phases (9 barriers, was 12): 0 idx/xm/sincos | 1 gather||mm1 | 2 mm2
//   (h->A, kvpe->regs) | 3 mm3(u) | 4+5 mm4 + reg-softmax + attn + wsum
//   -> res16 | 6 fc2 MFMA
// ---------------------------------------------------------------------------
__global__ __launch_bounds__(256, 3) void fused_kernel(
    const __hip_bfloat16* __restrict__ x_bf,
    const float* __restrict__ xyz,
    const int*   __restrict__ knn_idx,
    const float* __restrict__ knn_xyz,
    const __hip_bfloat16* __restrict__ wbuf,
    const float* __restrict__ d1_b, const float* __restrict__ d2_b,
    const float* __restrict__ g1_b, const float* __restrict__ g2_b,
    const float* __restrict__ fc2_b,
    float* __restrict__ out_res,
    float* __restrict__ out_attn)
{
    __shared__ alignas(16) __hip_bfloat16 s_A[RR * LDA128];
    __shared__ alignas(16) __hip_bfloat16 s_Z[RR * DM];
    __shared__ alignas(16) __hip_bfloat16 s_xm[PPB * DM];

    __hip_bfloat16* s_ge = s_A;                               // stride LDA64, dead after mm1
    int* s_idx = reinterpret_cast<int*>(s_A + RR * LDA64);    // tail, dead after gather issue

    const int tid = threadIdx.x;
    const int pt0 = blockIdx.x * PPB;
    const int b   = pt0 >> 14;
    const int w = tid >> 6, lane = tid & 63;
    const int ln = lane & 15, quad = lane >> 4;
    const int c0 = w * 32;
    const bool lo = (quad < 2);           // straddler-mt routing: quads 0-1 = low point

    // ---- phase 0: idx, xm, sincos embedding ----
    if (tid < RR) s_idx[tid] = knn_idx[(size_t)pt0 * KK + tid];
    if (tid < PPB * DM / 8)
        *reinterpret_cast<v8bf*>(s_xm + tid * 8) =
            *(const v8bf*)(x_bf + (size_t)pt0 * DM + tid * 8);
    if (tid < RR)                         // zero k-pad cols 60..63 of g_emb
        *reinterpret_cast<uint2*>(s_ge + tid * LDA64 + 60) = make_uint2(0u, 0u);
    for (int e = tid; e < RR * 30; e += 256) {
        const int row = e / 30;
        const int rem = e - row * 30;
        const int c = rem / 10;
        const int i = rem - c * 10;
        const int g = pt0 + row / 24;
        const float pv = xyz[(size_t)g * 3 + c] - knn_xyz[((size_t)pt0 * KK + row) * 3 + c];
        const float om = exp2f(-(float)i * 1.3287712379549449f); // 10000^(-i/10)
        float sv, cv;
        __sincosf(pv * om, &sv, &cv);
        s_ge[row * LDA64 + c * 20 + i]      = __float2bfloat16(sv);
        s_ge[row * LDA64 + c * 20 + 10 + i] = __float2bfloat16(cv);
    }
    __syncthreads();

    v4f acc[6][2];

    // ---- phase 1: kv gather (issue early) || mm1: t = relu(ge@d1+b) ----
    v8bf gv[6];
    {
        const size_t xbase = (size_t)b * NN * DM;
        #pragma unroll
        for (int i = 0; i < 6; ++i) {
            const int e = tid + i * 256;
            const int row = e >> 4, part = e & 15;
            gv[i] = *(const v8bf*)(x_bf + xbase + (size_t)s_idx[row] * DM + part * 8);
        }
    }
    mm_frags<6, 2, LDA64, 64>(s_A, wbuf + OFF_D1T, c0, lane, acc);
    #pragma unroll
    for (int i = 0; i < 6; ++i) {         // write-late: HBM latency hidden under mm1
        const int e = tid + i * 256;
        const int row = e >> 4, part = e & 15;
        *reinterpret_cast<v8bf*>(&s_Z[zoff(row, part * 8)]) = gv[i];
    }
    __syncthreads();                      // ge reads done; s_Z gather visible
    {
        const float bb0 = d1_b[c0 + ln], bb1 = d1_b[c0 + 16 + ln];
        #pragma unroll
        for (int mt = 0; mt < 6; ++mt) {
            const int row0 = mt * 16 + quad * 4;
            #pragma unroll
            for (int r = 0; r < 4; ++r) {
                s_A[(row0 + r) * LDA128 + c0 + ln]      = __float2bfloat16(fmaxf(acc[mt][0][r] + bb0, 0.f));
                s_A[(row0 + r) * LDA128 + c0 + 16 + ln] = __float2bfloat16(fmaxf(acc[mt][1][r] + bb1, 0.f));
            }
        }
    }
    __syncthreads();

    // ---- phase 2: pe = t@d2+b; h = xm-kv+pe -> A; kvpe -> regs (bf16 pairs)
    mm_frags<6, 4, LDA128, DM>(s_A, wbuf + OFF_D2T, c0, lane, acc);
    __syncthreads();                      // t reads done
    unsigned kvpk[6][2][2];
    {
        const float bb0 = d2_b[c0 + ln], bb1 = d2_b[c0 + 16 + ln];
        #pragma unroll
        for (int mt = 0; mt < 6; ++mt) {
            constexpr int pl_[6] = {0,0,1,2,2,3};
            constexpr int ph_[6] = {0,1,1,2,3,3};
            const int row0 = mt * 16 + quad * 4;
            const int p = (pl_[mt] == ph_[mt]) ? pl_[mt] : (lo ? pl_[mt] : ph_[mt]);
            const float xm0 = __bfloat162float(s_xm[p * DM + c0 + ln]);
            const float xm1 = __bfloat162float(s_xm[p * DM + c0 + 16 + ln]);
            float kp0[4], kp1[4];
            #pragma unroll
            for (int r = 0; r < 4; ++r) {
                const int row = row0 + r;
                const float pe0 = acc[mt][0][r] + bb0;
                const float pe1 = acc[mt][1][r] + bb1;
                const float kv0 = __bfloat162float(s_Z[zoff(row, c0 + ln)]);
                const float kv1 = __bfloat162float(s_Z[zoff(row, c0 + 16 + ln)]);
                s_A[row * LDA128 + c0 + ln]      = __float2bfloat16(xm0 - kv0 + pe0);
                s_A[row * LDA128 + c0 + 16 + ln] = __float2bfloat16(xm1 - kv1 + pe1);
                kp0[r] = kv0 + pe0;
                kp1[r] = kv1 + pe1;
            }
            kvpk[mt][0][0] = pk2(kp0[0], kp0[1]);
            kvpk[mt][0][1] = pk2(kp0[2], kp0[3]);
            kvpk[mt][1][0] = pk2(kp1[0], kp1[1]);
            kvpk[mt][1][1] = pk2(kp1[2], kp1[3]);
        }
    }
    __syncthreads();

    // ---- phase 3: u = relu(h@g1+b) -> A ----
    mm_frags<6, 4, LDA128, DM>(s_A, wbuf + OFF_G1T, c0, lane, acc);
    __syncthreads();
    {
        const float bb0 = g1_b[c0 + ln], bb1 = g1_b[c0 + 16 + ln];
        #pragma unroll
        for (int mt = 0; mt < 6; ++mt) {
            const int row0 = mt * 16 + quad * 4;
            #pragma unroll
            for (int r = 0; r < 4; ++r) {
                s_A[(row0 + r) * LDA128 + c0 + ln]      = __float2bfloat16(fmaxf(acc[mt][0][r] + bb0, 0.f));
                s_A[(row0 + r) * LDA128 + c0 + 16 + ln] = __float2bfloat16(fmaxf(acc[mt][1][r] + bb1, 0.f));
            }
        }
    }
    __syncthreads();

    // ---- phase 4+5: logits in regs -> register softmax -> attn + wsum ----
    mm_frags<6, 4, LDA128, DM>(s_A, wbuf + OFF_G2T, c0, lane, acc);
    {
        // log2-domain scale: softmax_e(x*iscl) == softmax via exp2(x*C), C=iscl*log2e
        const float C = 0.08838834764831845f * 1.4426950408889634f;
        const float sb0 = g2_b[c0 + ln] * C, sb1 = g2_b[c0 + 16 + ln] * C;
        #pragma unroll
        for (int mt = 0; mt < 6; ++mt)
            #pragma unroll
            for (int r = 0; r < 4; ++r) {
                acc[mt][0][r] = fmaf(acc[mt][0][r], C, sb0);
                acc[mt][1][r] = fmaf(acc[mt][1][r], C, sb1);
            }

        constexpr int pl_[6] = {0,0,1,2,2,3};
        constexpr int ph_[6] = {0,1,1,2,3,3};

        // per-point max: local accumulate (static routing) then quad reduce
        float mx[4][2];
        #pragma unroll
        for (int p = 0; p < 4; ++p) { mx[p][0] = -1e30f; mx[p][1] = -1e30f; }
        #pragma unroll
        for (int mt = 0; mt < 6; ++mt)
            #pragma unroll
            for (int nl = 0; nl < 2; ++nl) {
                const float m4 = fmaxf(fmaxf(acc[mt][nl][0], acc[mt][nl][1]),
                                       fmaxf(acc[mt][nl][2], acc[mt][nl][3]));
                if (pl_[mt] == ph_[mt]) {
                    mx[pl_[mt]][nl] = fmaxf(mx[pl_[mt]][nl], m4);
                } else {
                    mx[pl_[mt]][nl] = fmaxf(mx[pl_[mt]][nl], lo ? m4 : -1e30f);
                    mx[ph_[mt]][nl] = fmaxf(mx[ph_[mt]][nl], lo ? -1e30f : m4);
                }
            }
        #pragma unroll
        for (int p = 0; p < 4; ++p)
            #pragma unroll
            for (int nl = 0; nl < 2; ++nl) {
                float v = mx[p][nl];
                v = fmaxf(v, __shfl_xor(v, 16));
                v = fmaxf(v, __shfl_xor(v, 32));
                mx[p][nl] = v;
            }

        // e = exp2(L - mx), per-point sums
        float sm[4][2];
        #pragma unroll
        for (int p = 0; p < 4; ++p) { sm[p][0] = 0.f; sm[p][1] = 0.f; }
        #pragma unroll
        for (int mt = 0; mt < 6; ++mt)
            #pragma unroll
            for (int nl = 0; nl < 2; ++nl) {
                const float mxv = (pl_[mt] == ph_[mt]) ? mx[pl_[mt]][nl]
                                  : (lo ? mx[pl_[mt]][nl] : mx[ph_[mt]][nl]);
                float es = 0.f;
                #pragma unroll
                for (int r = 0; r < 4; ++r) {
                    const float e = exp2f(acc[mt][nl][r] - mxv);
                    acc[mt][nl][r] = e;
                    es += e;
                }
                if (pl_[mt] == ph_[mt]) {
                    sm[pl_[mt]][nl] += es;
                } else {
                    sm[pl_[mt]][nl] += lo ? es : 0.f;
                    sm[ph_[mt]][nl] += lo ? 0.f : es;
                }
            }
        #pragma unroll
        for (int p = 0; p < 4; ++p)
            #pragma unroll
            for (int nl = 0; nl < 2; ++nl) {
                float v = sm[p][nl];
                v += __shfl_xor(v, 16);
                v += __shfl_xor(v, 32);
                sm[p][nl] = 1.f / v;       // now holds inv-sum
            }

        // attn = e*inv -> global (p cancels: row index = pt0*24 + rowg);
        // weighted sum rp[p][nl] += attn * kvpe (kvpe from phase-2 regs)
        float rp[4][2];
        #pragma unroll
        for (int p = 0; p < 4; ++p) { rp[p][0] = 0.f; rp[p][1] = 0.f; }
        float* abase = out_attn + (size_t)pt0 * KK * DM;
        #pragma unroll
        for (int mt = 0; mt < 6; ++mt) {
            const int rowg0 = mt * 16 + quad * 4;
            #pragma unroll
            for (int nl = 0; nl < 2; ++nl) {
                const int col = c0 + nl * 16 + ln;
                const float invv = (pl_[mt] == ph_[mt]) ? sm[pl_[mt]][nl]
                                   : (lo ? sm[pl_[mt]][nl] : sm[ph_[mt]][nl]);
                const float kv0 = unlo(kvpk[mt][nl][0]);
                const float kv1 = unhi(kvpk[mt][nl][0]);
                const float kv2 = unlo(kvpk[mt][nl][1]);
                const float kv3 = unhi(kvpk[mt][nl][1]);
                const float a0 = acc[mt][nl][0] * invv;
                const float a1 = acc[mt][nl][1] * invv;
                const float a2 = acc[mt][nl][2] * invv;
                const float a3 = acc[mt][nl][3] * invv;
                abase[(size_t)(rowg0 + 0) * DM + col] = a0;
                abase[(size_t)(rowg0 + 1) * DM + col] = a1;
                abase[(size_t)(rowg0 + 2) * DM + col] = a2;
                abase[(size_t)(rowg0 + 3) * DM + col] = a3;
                const float ws = fmaf(a0, kv0, fmaf(a1, kv1, fmaf(a2, kv2, a3 * kv3)));
                if (pl_[mt] == ph_[mt]) {
                    rp[pl_[mt]][nl] += ws;
                } else {
                    rp[pl_[mt]][nl] += lo ? ws : 0.f;
                    rp[ph_[mt]][nl] += lo ? 0.f : ws;
                }
            }
        }
        #pragma unroll
        for (int p = 0; p < 4; ++p)
            #pragma unroll
            for (int nl = 0; nl < 2; ++nl) {
                float v = rp[p][nl];
                v += __shfl_xor(v, 16);
                v += __shfl_xor(v, 32);
                rp[p][nl] = v;
            }

        __syncthreads();                  // all mm4 A-reads done -> reuse rows 0..3
        if (quad == 0) {                  // res16: rows 0..3 real; 4..15 stale u (finite)
            #pragma unroll
            for (int p = 0; p < 4; ++p) {
                s_A[p * LDA128 + c0 + ln]      = __float2bfloat16(rp[p][0]);
                s_A[p * LDA128 + c0 + 16 + ln] = __float2bfloat16(rp[p][1]);
            }
        }
    }
    __syncthreads();

    // ---- phase 6: out_res rows = res16 @ fc2t via one 16-row MFMA tile ----
    {
        v4f a2[1][2];
        mm_frags<1, 4, LDA128, DM>(s_A, wbuf + OFF_FC2T, c0, lane, a2);
        if (quad == 0) {                  // D rows 0..3 are the real points
            #pragma unroll
            for (int nl = 0; nl < 2; ++nl) {
                const int col = c0 + nl * 16 + ln;
                const float bb = fc2_b[col];
                #pragma unroll
                for (int r = 0; r < 4; ++r)
                    out_res[(size_t)(pt0 + r) * DM + col] =
                        a2[0][nl][r] + bb + __bfloat162float(s_xm[r * DM + col]);
            }
        }
    }
}

// ---------------------------------------------------------------------------
extern "C" void kernel_launch(void* const* d_in, const int* in_sizes, int n_in,
                              void* d_out, int out_size, void* d_ws, size_t ws_size,
                              hipStream_t stream)
{
    const float* features = (const float*)d_in[0];
    const float* xyz      = (const float*)d_in[1];
    const int*   knn_idx  = (const int*)  d_in[2];
    const float* knn_xyz  = (const float*)d_in[3];
    const float* fc1_w    = (const float*)d_in[4];
    const float* fc1_b    = (const float*)d_in[5];
    const float* fc2_w    = (const float*)d_in[6];
    const float* fc2_b    = (const float*)d_in[7];
    const float* d1_w     = (const float*)d_in[8];
    const float* d1_b     = (const float*)d_in[9];
    const float* d2_w     = (const float*)d_in[10];
    const float* d2_b     = (const float*)d_in[11];
    const float* g1_w     = (const float*)d_in[12];
    const float* g1_b     = (const float*)d_in[13];
    const float* g2_w     = (const float*)d_in[14];
    const float* g2_b     = (const float*)d_in[15];

    __hip_bfloat16* x_bf = (__hip_bfloat16*)d_ws;                  // B*N*128 bf16 = 8 MB
    __hip_bfloat16* wbuf = x_bf + (size_t)BB * NN * DM;            // 160 KB bf16 weights
    float* out_res  = (float*)d_out;
    float* out_attn = out_res + (size_t)BB * NN * DM;

    prep_kernel<<<(W_TOTAL + 255) / 256, 256, 0, stream>>>(
        fc1_w, fc2_w, d1_w, d2_w, g1_w, g2_w, wbuf);
    fc1_kernel<<<(BB * NN) / 32, 256, 0, stream>>>(
        features, wbuf + OFF_FC1T, fc1_b, x_bf);
    fused_kernel<<<(BB * NN) / PPB, 256, 0, stream>>>(
        x_bf, xyz, knn_idx, knn_xyz, wbuf,
        d1_b, d2_b, g1_b, g2_b, fc2_b, out_res, out_attn);
}